// Round 5
// baseline (1262.279 us; speedup 1.0000x reference)
//
#include <hip/hip_runtime.h>

#define HID 256
#define IN_CH 512
#define NPAD 50176

#define CHCH 32      // channels per chunk (128 B = one L2 line)
#define NCHUNK 8
#define AGG_NPW 16   // nodes per wave
#define AGG_NPB 64   // nodes per block (4 waves)

typedef __attribute__((ext_vector_type(8))) short s16x8;
typedef __attribute__((ext_vector_type(4))) float f32x4;

#define GLBP(p) ((const __attribute__((address_space(1))) void*)(p))
#define LDSP(p) ((__attribute__((address_space(3))) void*)(p))

// ---------------- CSR build ----------------

__global__ __launch_bounds__(256) void k_count(const int* __restrict__ dst,
                                               int* __restrict__ cnt, int E) {
    int e = blockIdx.x * 256 + threadIdx.x;
    if (e < E) atomicAdd(&cnt[dst[e]], 1);
}

__global__ __launch_bounds__(256) void k_scan_bsum(const int* __restrict__ cnt,
                                                   int* __restrict__ bsum, int n) {
    __shared__ int sdata[256];
    int t = threadIdx.x;
    int base = blockIdx.x * 1024 + t * 4;
    int s = 0;
#pragma unroll
    for (int j = 0; j < 4; ++j) if (base + j < n) s += cnt[base + j];
    sdata[t] = s;
    __syncthreads();
    for (int off = 128; off > 0; off >>= 1) {
        if (t < off) sdata[t] += sdata[t + off];
        __syncthreads();
    }
    if (t == 0) bsum[blockIdx.x] = sdata[0];
}

__global__ __launch_bounds__(64) void k_scan_boff(const int* __restrict__ bsum,
                                                  int* __restrict__ boff, int nb) {
    int lane = threadIdx.x;
    int own = (lane < nb) ? bsum[lane] : 0;
    int v = own;
    for (int off = 1; off < 64; off <<= 1) {
        int u = __shfl_up(v, off, 64);
        if (lane >= off) v += u;
    }
    if (lane < nb) boff[lane] = v - own;
}

__global__ __launch_bounds__(256) void k_scan_write(const int* __restrict__ cnt,
                                                    const int* __restrict__ boff,
                                                    int* __restrict__ rowptr, int n) {
    __shared__ int sdata[256];
    int t = threadIdx.x;
    int base = blockIdx.x * 1024 + t * 4;
    int c0 = (base + 0 < n) ? cnt[base + 0] : 0;
    int c1 = (base + 1 < n) ? cnt[base + 1] : 0;
    int c2 = (base + 2 < n) ? cnt[base + 2] : 0;
    int c3 = (base + 3 < n) ? cnt[base + 3] : 0;
    int tsum = c0 + c1 + c2 + c3;
    sdata[t] = tsum;
    __syncthreads();
    for (int off = 1; off < 256; off <<= 1) {
        int v = (t >= off) ? sdata[t - off] : 0;
        __syncthreads();
        if (t >= off) sdata[t] += v;
        __syncthreads();
    }
    int excl = sdata[t] - tsum;
    int p = boff[blockIdx.x] + excl;
    if (base + 0 < n) rowptr[base + 1] = p + c0;
    if (base + 1 < n) rowptr[base + 2] = p + c0 + c1;
    if (base + 2 < n) rowptr[base + 3] = p + c0 + c1 + c2;
    if (base + 3 < n) rowptr[base + 4] = p + c0 + c1 + c2 + c3;
    if (blockIdx.x == 0 && t == 0) rowptr[0] = 0;
}

__global__ __launch_bounds__(256) void k_dinv(const int* __restrict__ cnt,
                                              float* __restrict__ dinv, int n) {
    int i = blockIdx.x * 256 + threadIdx.x;
    if (i < n) dinv[i] = rsqrtf((float)(cnt[i] + 1));
}

// fill sorted edge records {src, norm} (dinv must be ready)
__global__ __launch_bounds__(256) void k_fill(const int* __restrict__ src,
                                              const int* __restrict__ dst,
                                              const int* __restrict__ rowptr,
                                              int* __restrict__ cursor,
                                              const float* __restrict__ dinv,
                                              int2* __restrict__ erec, int E) {
    int e = blockIdx.x * 256 + threadIdx.x;
    if (e >= E) return;
    int d = dst[e];
    int s = src[e];
    int pos = rowptr[d] + atomicAdd(&cursor[d], 1);
    float w = dinv[s] * dinv[d];
    erec[pos] = make_int2(s, __float_as_int(w));
}

// ---------------- weight pre-split: W[K][256] fp32 -> Bt'[K/32][256][104] bf16 ----------------

__global__ __launch_bounds__(256) void k_wsplit(const float* __restrict__ W,
                                                unsigned short* __restrict__ Bt,
                                                int K) {
    int t = blockIdx.x * 256 + threadIdx.x;
    if (t >= K * HID) return;
    int n = t & 255;
    int k = t >> 8;
    float w = W[(size_t)k * HID + n];
    unsigned int u = __float_as_uint(w);
    unsigned short hi = (unsigned short)(u >> 16);
    float hif = __uint_as_float(u & 0xffff0000u);
    float lo = w - hif;
    unsigned short lob = (unsigned short)(__float_as_uint(lo) >> 16);
    unsigned short* p = Bt + (size_t)(k >> 5) * (HID * 104) + n * 104 + 3 * (k & 31);
    p[0] = hi; p[1] = hi; p[2] = lob;
}

// ---------------- MFMA GEMM (unchanged from round 3) ----------------

template<bool RELU>
__global__ __launch_bounds__(512) void k_gemm_mfma(const float* __restrict__ A,
                                                   const unsigned short* __restrict__ Bt,
                                                   float* __restrict__ C,
                                                   int M, int Korig) {
    __shared__ unsigned short Als[128 * 104];
    __shared__ unsigned short Bls[256 * 104];

    const int m0 = blockIdx.x * 128;
    const int tid = threadIdx.x;
    const int wave = tid >> 6;
    const int lane = tid & 63;
    const int wm = wave >> 2;
    const int wn = wave & 3;

    f32x4 acc[4][4] = {};

    const int nsteps = Korig >> 5;
    const int arow = tid >> 2;
    const int aseg = (tid & 3) * 8;

    for (int ks = 0; ks < nsteps; ++ks) {
        {
            int gm = m0 + arow;
            float4 v0 = make_float4(0, 0, 0, 0), v1 = v0;
            if (gm < M) {
                const float* ap = A + (size_t)gm * Korig + ks * 32 + aseg;
                v0 = *(const float4*)ap;
                v1 = *(const float4*)(ap + 4);
            }
            float av[8] = {v0.x, v0.y, v0.z, v0.w, v1.x, v1.y, v1.z, v1.w};
            unsigned short hi[8], lo[8];
#pragma unroll
            for (int j = 0; j < 8; ++j) {
                float a = av[j];
                if (RELU) a = fmaxf(a, 0.f);
                unsigned int u = __float_as_uint(a);
                hi[j] = (unsigned short)(u >> 16);
                float hif = __uint_as_float(u & 0xffff0000u);
                float l = a - hif;
                lo[j] = (unsigned short)(__float_as_uint(l) >> 16);
            }
            s16x8 w0 = {(short)hi[0], (short)lo[0], (short)hi[0], (short)hi[1],
                        (short)lo[1], (short)hi[1], (short)hi[2], (short)lo[2]};
            s16x8 w1 = {(short)hi[2], (short)hi[3], (short)lo[3], (short)hi[3],
                        (short)hi[4], (short)lo[4], (short)hi[4], (short)hi[5]};
            s16x8 w2 = {(short)lo[5], (short)hi[5], (short)hi[6], (short)lo[6],
                        (short)hi[6], (short)hi[7], (short)lo[7], (short)hi[7]};
            s16x8* dp = (s16x8*)&Als[arow * 104 + (tid & 3) * 24];
            dp[0] = w0; dp[1] = w1; dp[2] = w2;
        }
        {
            const char* src = (const char*)(Bt + (size_t)ks * (HID * 104));
            for (int g = wave; g < 52; g += 8) {
                int byteoff = (g * 64 + lane) * 16;
                __builtin_amdgcn_global_load_lds(GLBP(src + byteoff),
                                                 LDSP((char*)Bls + byteoff), 16, 0, 0);
            }
        }
        __syncthreads();

#pragma unroll
        for (int kk = 0; kk < 3; ++kk) {
            int gsh = (kk * 4 + (lane >> 4)) * 8;
            s16x8 af[4], bf[4];
#pragma unroll
            for (int mf = 0; mf < 4; ++mf) {
                int row = wm * 64 + mf * 16 + (lane & 15);
                af[mf] = *(const s16x8*)&Als[row * 104 + gsh];
            }
#pragma unroll
            for (int nf = 0; nf < 4; ++nf) {
                int col = wn * 64 + nf * 16 + (lane & 15);
                bf[nf] = *(const s16x8*)&Bls[col * 104 + gsh];
            }
#pragma unroll
            for (int mf = 0; mf < 4; ++mf)
#pragma unroll
                for (int nf = 0; nf < 4; ++nf)
                    acc[mf][nf] = __builtin_amdgcn_mfma_f32_16x16x32_bf16(af[mf], bf[nf],
                                                                          acc[mf][nf], 0, 0, 0);
        }
        __syncthreads();
    }

#pragma unroll
    for (int mf = 0; mf < 4; ++mf) {
        int row0 = m0 + wm * 64 + mf * 16 + (lane >> 4) * 4;
#pragma unroll
        for (int r = 0; r < 4; ++r) {
            int gr = row0 + r;
            if (gr < M) {
#pragma unroll
                for (int nf = 0; nf < 4; ++nf) {
                    int col = wn * 64 + nf * 16 + (lane & 15);
                    C[(size_t)gr * HID + col] = acc[mf][nf][r];
                }
            }
        }
    }
}

// ---------------- chunked gather aggregate: chunk (bid&7) -> XCD affinity ----------------
// Each block: one 32-channel chunk, 64 nodes (4 waves x 16). Wave: 2 edge-halves x 32 ch.

__global__ __launch_bounds__(256) void k_agg_chunk(const float* __restrict__ h,
                                                   const float* __restrict__ dinv,
                                                   const int2* __restrict__ erec,
                                                   const int* __restrict__ rowptr,
                                                   const float* __restrict__ bias,
                                                   float* __restrict__ agg,
                                                   int n) {
    const int chunk = blockIdx.x & 7;
    const int nblk  = blockIdx.x >> 3;
    const int c0 = chunk * CHCH;
    const int wave = threadIdx.x >> 6;
    const int lane = threadIdx.x & 63;
    const int half = lane >> 5;       // which edge of the pair
    const int ch   = lane & 31;       // channel within chunk

    const float bch = bias[c0 + ch];
    const int node0 = nblk * AGG_NPB + wave * AGG_NPW;
    const int nodeEnd = min(node0 + AGG_NPW, n);

    for (int node = node0; node < nodeEnd; ++node) {
        const int e0 = rowptr[node];
        const int e1 = rowptr[node + 1];
        float acc = 0.f;

        for (int base = e0; base < e1; base += 64) {
            int cnt = min(64, e1 - base);
            long long rv = 0;
            if (lane < cnt)
                rv = __builtin_nontemporal_load((const long long*)&erec[base + lane]);
            int ridx = (int)(rv & 0xffffffffLL);
            int rwb  = (int)(rv >> 32);

            for (int j = 0; j < cnt; j += 2) {
                int jj = j + half;
                int sidx = __shfl(ridx, jj, 64);
                int wb   = __shfl(rwb,  jj, 64);
                bool valid = jj < cnt;
                float w = valid ? __uint_as_float((unsigned)wb) : 0.f;
                if (!valid) sidx = 0;
                float v = h[(size_t)sidx * HID + c0 + ch];
                acc += v * w;
            }
        }
        // combine the two edge-halves (lanes l and l^32 hold same channel)
        acc += __shfl_xor(acc, 32, 64);
        if (half == 0) {
            float dd = dinv[node];
            float self = h[(size_t)node * HID + c0 + ch];
            agg[(size_t)node * HID + c0 + ch] = acc + bch + self * dd * dd;
        }
    }
}

// ---------------- readout: out[n] = bout + sum_c relu(agg[n][c]) * Wout[c] ----------------

__global__ __launch_bounds__(256) void k_readout(const float* __restrict__ h,
                                                 const float* __restrict__ wout,
                                                 const float* __restrict__ bout,
                                                 float* __restrict__ out, int n) {
    int node = blockIdx.x * 4 + (threadIdx.x >> 6);
    if (node >= n) return;
    int lane = threadIdx.x & 63;
    float4 v = *(const float4*)(h + (size_t)node * HID + lane * 4);
    float4 w = *(const float4*)(wout + lane * 4);
    v.x = fmaxf(v.x, 0.f); v.y = fmaxf(v.y, 0.f);
    v.z = fmaxf(v.z, 0.f); v.w = fmaxf(v.w, 0.f);
    float s = v.x * w.x + v.y * w.y + v.z * w.z + v.w * w.w;
#pragma unroll
    for (int off = 32; off > 0; off >>= 1) s += __shfl_down(s, off, 64);
    if (lane == 0) out[node] = s + bout[0];
}

// ---------------- launch ----------------

extern "C" void kernel_launch(void* const* d_in, const int* in_sizes, int n_in,
                              void* d_out, int out_size, void* d_ws, size_t ws_size,
                              hipStream_t stream) {
    const float* x    = (const float*)d_in[0];
    const int*   ei   = (const int*)d_in[1];
    const float* W0   = (const float*)d_in[2];
    const float* b0   = (const float*)d_in[3];
    const float* W1   = (const float*)d_in[4];
    const float* b1   = (const float*)d_in[5];
    const float* W2   = (const float*)d_in[6];
    const float* b2   = (const float*)d_in[7];
    const float* Wout = (const float*)d_in[8];
    const float* bout = (const float*)d_in[9];
    float* out = (float*)d_out;

    const int n = in_sizes[0] / IN_CH;   // 50000
    const int E = in_sizes[1] / 2;       // 800000
    const int* src = ei;
    const int* dst = ei + E;

    // workspace carve-up
    float* dinv   = (float*)d_ws;                        // NPAD
    int*   rowptr = (int*)(dinv + NPAD);                 // NPAD
    int*   cursor = rowptr + NPAD;                       // NPAD
    int2*  erec   = (int2*)(cursor + NPAD);              // E (8B each)
    int*   bsum   = (int*)(erec + 800000);               // 64
    int*   boff   = bsum + 64;                           // 64
    unsigned short* Bt0 = (unsigned short*)(boff + 64);  // 16*256*104
    unsigned short* Bt1 = Bt0 + 16 * HID * 104;          // 8*256*104
    unsigned short* Bt2 = Bt1 + 8 * HID * 104;           // 8*256*104
    float* bufA   = (float*)(Bt2 + 8 * HID * 104);       // n*HID
    float* bufB   = bufA + (size_t)n * HID;              // n*HID

    const int nb_n = (n + 255) / 256;
    const int nb_e = (E + 255) / 256;
    const int nb_scan = (n + 1023) / 1024;

    // ---- CSR build ----
    hipMemsetAsync(cursor, 0, (size_t)n * 4, stream);
    k_count<<<nb_e, 256, 0, stream>>>(dst, cursor, E);
    k_scan_bsum<<<nb_scan, 256, 0, stream>>>(cursor, bsum, n);
    k_scan_boff<<<1, 64, 0, stream>>>(bsum, boff, nb_scan);
    k_scan_write<<<nb_scan, 256, 0, stream>>>(cursor, boff, rowptr, n);
    k_dinv<<<nb_n, 256, 0, stream>>>(cursor, dinv, n);
    hipMemsetAsync(cursor, 0, (size_t)n * 4, stream);
    k_fill<<<nb_e, 256, 0, stream>>>(src, dst, rowptr, cursor, dinv, erec, E);

    // ---- weight pre-split ----
    k_wsplit<<<(IN_CH * HID) / 256, 256, 0, stream>>>(W0, Bt0, IN_CH);
    k_wsplit<<<(HID * HID) / 256, 256, 0, stream>>>(W1, Bt1, HID);
    k_wsplit<<<(HID * HID) / 256, 256, 0, stream>>>(W2, Bt2, HID);

    const int gemm_blocks = (n + 127) / 128;
    const int agg_nb = (n + AGG_NPB - 1) / AGG_NPB;      // node blocks
    const int agg_blocks = NCHUNK * agg_nb;              // chunk-major in bid&7
    const int ro_blocks = (n + 3) / 4;

    // layer 0
    k_gemm_mfma<false><<<gemm_blocks, 512, 0, stream>>>(x, Bt0, bufA, n, IN_CH);
    k_agg_chunk<<<agg_blocks, 256, 0, stream>>>(bufA, dinv, erec, rowptr, b0, bufB, n);
    // layer 1
    k_gemm_mfma<true><<<gemm_blocks, 512, 0, stream>>>(bufB, Bt1, bufA, n, HID);
    k_agg_chunk<<<agg_blocks, 256, 0, stream>>>(bufA, dinv, erec, rowptr, b1, bufB, n);
    // layer 2
    k_gemm_mfma<true><<<gemm_blocks, 512, 0, stream>>>(bufB, Bt2, bufA, n, HID);
    k_agg_chunk<<<agg_blocks, 256, 0, stream>>>(bufA, dinv, erec, rowptr, b2, bufB, n);
    // readout
    k_readout<<<ro_blocks, 256, 0, stream>>>(bufB, Wout, bout, out, n);
}

// Round 6
// 566.036 us; speedup vs baseline: 2.2300x; 2.2300x over previous
//
#include <hip/hip_runtime.h>

#define HID 256
#define IN_CH 512
#define NPAD 50176

typedef __attribute__((ext_vector_type(8))) short s16x8;
typedef __attribute__((ext_vector_type(4))) float f32x4;
typedef __attribute__((ext_vector_type(4))) _Float16 f16x4;

#define GLBP(p) ((const __attribute__((address_space(1))) void*)(p))
#define LDSP(p) ((__attribute__((address_space(3))) void*)(p))

// ---------------- CSR build ----------------

__global__ __launch_bounds__(256) void k_count(const int* __restrict__ dst,
                                               int* __restrict__ cnt, int E) {
    int e = blockIdx.x * 256 + threadIdx.x;
    if (e < E) atomicAdd(&cnt[dst[e]], 1);
}

__global__ __launch_bounds__(256) void k_scan_bsum(const int* __restrict__ cnt,
                                                   int* __restrict__ bsum, int n) {
    __shared__ int sdata[256];
    int t = threadIdx.x;
    int base = blockIdx.x * 1024 + t * 4;
    int s = 0;
#pragma unroll
    for (int j = 0; j < 4; ++j) if (base + j < n) s += cnt[base + j];
    sdata[t] = s;
    __syncthreads();
    for (int off = 128; off > 0; off >>= 1) {
        if (t < off) sdata[t] += sdata[t + off];
        __syncthreads();
    }
    if (t == 0) bsum[blockIdx.x] = sdata[0];
}

__global__ __launch_bounds__(64) void k_scan_boff(const int* __restrict__ bsum,
                                                  int* __restrict__ boff, int nb) {
    int lane = threadIdx.x;
    int own = (lane < nb) ? bsum[lane] : 0;
    int v = own;
    for (int off = 1; off < 64; off <<= 1) {
        int u = __shfl_up(v, off, 64);
        if (lane >= off) v += u;
    }
    if (lane < nb) boff[lane] = v - own;
}

__global__ __launch_bounds__(256) void k_scan_write(const int* __restrict__ cnt,
                                                    const int* __restrict__ boff,
                                                    int* __restrict__ rowptr, int n) {
    __shared__ int sdata[256];
    int t = threadIdx.x;
    int base = blockIdx.x * 1024 + t * 4;
    int c0 = (base + 0 < n) ? cnt[base + 0] : 0;
    int c1 = (base + 1 < n) ? cnt[base + 1] : 0;
    int c2 = (base + 2 < n) ? cnt[base + 2] : 0;
    int c3 = (base + 3 < n) ? cnt[base + 3] : 0;
    int tsum = c0 + c1 + c2 + c3;
    sdata[t] = tsum;
    __syncthreads();
    for (int off = 1; off < 256; off <<= 1) {
        int v = (t >= off) ? sdata[t - off] : 0;
        __syncthreads();
        if (t >= off) sdata[t] += v;
        __syncthreads();
    }
    int excl = sdata[t] - tsum;
    int p = boff[blockIdx.x] + excl;
    if (base + 0 < n) rowptr[base + 1] = p + c0;
    if (base + 1 < n) rowptr[base + 2] = p + c0 + c1;
    if (base + 2 < n) rowptr[base + 3] = p + c0 + c1 + c2;
    if (base + 3 < n) rowptr[base + 4] = p + c0 + c1 + c2 + c3;
    if (blockIdx.x == 0 && t == 0) rowptr[0] = 0;
}

__global__ __launch_bounds__(256) void k_dinv(const int* __restrict__ cnt,
                                              float* __restrict__ dinv, int n) {
    int i = blockIdx.x * 256 + threadIdx.x;
    if (i < n) dinv[i] = rsqrtf((float)(cnt[i] + 1));
}

// fill sorted edge records {src, norm} (dinv must be ready)
__global__ __launch_bounds__(256) void k_fill(const int* __restrict__ src,
                                              const int* __restrict__ dst,
                                              const int* __restrict__ rowptr,
                                              int* __restrict__ cursor,
                                              const float* __restrict__ dinv,
                                              int2* __restrict__ erec, int E) {
    int e = blockIdx.x * 256 + threadIdx.x;
    if (e >= E) return;
    int d = dst[e];
    int s = src[e];
    int pos = rowptr[d] + atomicAdd(&cursor[d], 1);
    float w = dinv[s] * dinv[d];
    erec[pos] = make_int2(s, __float_as_int(w));
}

// ---------------- weight pre-split: W[K][256] fp32 -> Bt'[K/32][256][104] bf16 ----------------

__global__ __launch_bounds__(256) void k_wsplit(const float* __restrict__ W,
                                                unsigned short* __restrict__ Bt,
                                                int K) {
    int t = blockIdx.x * 256 + threadIdx.x;
    if (t >= K * HID) return;
    int n = t & 255;
    int k = t >> 8;
    float w = W[(size_t)k * HID + n];
    unsigned int u = __float_as_uint(w);
    unsigned short hi = (unsigned short)(u >> 16);
    float hif = __uint_as_float(u & 0xffff0000u);
    float lo = w - hif;
    unsigned short lob = (unsigned short)(__float_as_uint(lo) >> 16);
    unsigned short* p = Bt + (size_t)(k >> 5) * (HID * 104) + n * 104 + 3 * (k & 31);
    p[0] = hi; p[1] = hi; p[2] = lob;
}

// ---------------- MFMA GEMM: C16[M,256] = act(A)[M,K] @ W[K,256], fp16 output ----------------

template<bool RELU>
__global__ __launch_bounds__(512) void k_gemm_mfma(const float* __restrict__ A,
                                                   const unsigned short* __restrict__ Bt,
                                                   _Float16* __restrict__ C16,
                                                   int M, int Korig) {
    __shared__ unsigned short Als[128 * 104];
    __shared__ unsigned short Bls[256 * 104];

    const int m0 = blockIdx.x * 128;
    const int tid = threadIdx.x;
    const int wave = tid >> 6;
    const int lane = tid & 63;
    const int wm = wave >> 2;
    const int wn = wave & 3;

    f32x4 acc[4][4] = {};

    const int nsteps = Korig >> 5;
    const int arow = tid >> 2;
    const int aseg = (tid & 3) * 8;

    for (int ks = 0; ks < nsteps; ++ks) {
        {
            int gm = m0 + arow;
            float4 v0 = make_float4(0, 0, 0, 0), v1 = v0;
            if (gm < M) {
                const float* ap = A + (size_t)gm * Korig + ks * 32 + aseg;
                v0 = *(const float4*)ap;
                v1 = *(const float4*)(ap + 4);
            }
            float av[8] = {v0.x, v0.y, v0.z, v0.w, v1.x, v1.y, v1.z, v1.w};
            unsigned short hi[8], lo[8];
#pragma unroll
            for (int j = 0; j < 8; ++j) {
                float a = av[j];
                if (RELU) a = fmaxf(a, 0.f);
                unsigned int u = __float_as_uint(a);
                hi[j] = (unsigned short)(u >> 16);
                float hif = __uint_as_float(u & 0xffff0000u);
                float l = a - hif;
                lo[j] = (unsigned short)(__float_as_uint(l) >> 16);
            }
            s16x8 w0 = {(short)hi[0], (short)lo[0], (short)hi[0], (short)hi[1],
                        (short)lo[1], (short)hi[1], (short)hi[2], (short)lo[2]};
            s16x8 w1 = {(short)hi[2], (short)hi[3], (short)lo[3], (short)hi[3],
                        (short)hi[4], (short)lo[4], (short)hi[4], (short)hi[5]};
            s16x8 w2 = {(short)lo[5], (short)hi[5], (short)hi[6], (short)lo[6],
                        (short)hi[6], (short)hi[7], (short)lo[7], (short)hi[7]};
            s16x8* dp = (s16x8*)&Als[arow * 104 + (tid & 3) * 24];
            dp[0] = w0; dp[1] = w1; dp[2] = w2;
        }
        {
            const char* src = (const char*)(Bt + (size_t)ks * (HID * 104));
            for (int g = wave; g < 52; g += 8) {
                int byteoff = (g * 64 + lane) * 16;
                __builtin_amdgcn_global_load_lds(GLBP(src + byteoff),
                                                 LDSP((char*)Bls + byteoff), 16, 0, 0);
            }
        }
        __syncthreads();

#pragma unroll
        for (int kk = 0; kk < 3; ++kk) {
            int gsh = (kk * 4 + (lane >> 4)) * 8;
            s16x8 af[4], bf[4];
#pragma unroll
            for (int mf = 0; mf < 4; ++mf) {
                int row = wm * 64 + mf * 16 + (lane & 15);
                af[mf] = *(const s16x8*)&Als[row * 104 + gsh];
            }
#pragma unroll
            for (int nf = 0; nf < 4; ++nf) {
                int col = wn * 64 + nf * 16 + (lane & 15);
                bf[nf] = *(const s16x8*)&Bls[col * 104 + gsh];
            }
#pragma unroll
            for (int mf = 0; mf < 4; ++mf)
#pragma unroll
                for (int nf = 0; nf < 4; ++nf)
                    acc[mf][nf] = __builtin_amdgcn_mfma_f32_16x16x32_bf16(af[mf], bf[nf],
                                                                          acc[mf][nf], 0, 0, 0);
        }
        __syncthreads();
    }

#pragma unroll
    for (int mf = 0; mf < 4; ++mf) {
        int row0 = m0 + wm * 64 + mf * 16 + (lane >> 4) * 4;
#pragma unroll
        for (int r = 0; r < 4; ++r) {
            int gr = row0 + r;
            if (gr < M) {
#pragma unroll
                for (int nf = 0; nf < 4; ++nf) {
                    int col = wn * 64 + nf * 16 + (lane & 15);
                    C16[(size_t)gr * HID + col] = (_Float16)acc[mf][nf][r];
                }
            }
        }
    }
}

// ---------------- gather aggregate: one wave per dst node, fp16 h, fp32 accumulate ----------------
// agg[d] = bias + h[d]*dinv[d]^2 + sum_{(s,w) in row(d)} h[s]*w
// If READOUT: emit out[d] = bout + dot(relu(agg_row), wout)

template<bool READOUT>
__global__ __launch_bounds__(256) void k_aggregate(const _Float16* __restrict__ h,
                                                   const float* __restrict__ dinv,
                                                   const int* __restrict__ rowptr,
                                                   const int2* __restrict__ erec,
                                                   const float* __restrict__ bias,
                                                   float* __restrict__ agg,
                                                   const float* __restrict__ wout,
                                                   const float* __restrict__ bout,
                                                   float* __restrict__ out,
                                                   int n) {
    int node = blockIdx.x * 4 + (threadIdx.x >> 6);
    if (node >= n) return;
    int lane = threadIdx.x & 63;

    float dd = dinv[node];
    float4 acc;
    {
        float w = dd * dd;
        f16x4 v = *(const f16x4*)(h + (size_t)node * HID + lane * 4);
        float4 b = *(const float4*)(bias + lane * 4);
        acc = make_float4(b.x + (float)v[0] * w, b.y + (float)v[1] * w,
                          b.z + (float)v[2] * w, b.w + (float)v[3] * w);
    }

    int e = rowptr[node];
    int e_end = rowptr[node + 1];
    for (; e + 1 < e_end; e += 2) {
        int2 r0 = erec[e];
        int2 r1 = erec[e + 1];
        float w0 = __int_as_float(r0.y);
        float w1 = __int_as_float(r1.y);
        f16x4 v0 = *(const f16x4*)(h + (size_t)r0.x * HID + lane * 4);
        f16x4 v1 = *(const f16x4*)(h + (size_t)r1.x * HID + lane * 4);
        acc.x += (float)v0[0] * w0 + (float)v1[0] * w1;
        acc.y += (float)v0[1] * w0 + (float)v1[1] * w1;
        acc.z += (float)v0[2] * w0 + (float)v1[2] * w1;
        acc.w += (float)v0[3] * w0 + (float)v1[3] * w1;
    }
    if (e < e_end) {
        int2 r0 = erec[e];
        float w0 = __int_as_float(r0.y);
        f16x4 v0 = *(const f16x4*)(h + (size_t)r0.x * HID + lane * 4);
        acc.x += (float)v0[0] * w0; acc.y += (float)v0[1] * w0;
        acc.z += (float)v0[2] * w0; acc.w += (float)v0[3] * w0;
    }

    if (!READOUT) {
        *(float4*)(agg + (size_t)node * HID + lane * 4) = acc;
    } else {
        float4 w = *(const float4*)(wout + lane * 4);
        acc.x = fmaxf(acc.x, 0.f); acc.y = fmaxf(acc.y, 0.f);
        acc.z = fmaxf(acc.z, 0.f); acc.w = fmaxf(acc.w, 0.f);
        float s = acc.x * w.x + acc.y * w.y + acc.z * w.z + acc.w * w.w;
#pragma unroll
        for (int off = 32; off > 0; off >>= 1) s += __shfl_down(s, off, 64);
        if (lane == 0) out[node] = s + bout[0];
    }
}

// ---------------- launch ----------------

extern "C" void kernel_launch(void* const* d_in, const int* in_sizes, int n_in,
                              void* d_out, int out_size, void* d_ws, size_t ws_size,
                              hipStream_t stream) {
    const float* x    = (const float*)d_in[0];
    const int*   ei   = (const int*)d_in[1];
    const float* W0   = (const float*)d_in[2];
    const float* b0   = (const float*)d_in[3];
    const float* W1   = (const float*)d_in[4];
    const float* b1   = (const float*)d_in[5];
    const float* W2   = (const float*)d_in[6];
    const float* b2   = (const float*)d_in[7];
    const float* Wout = (const float*)d_in[8];
    const float* bout = (const float*)d_in[9];
    float* out = (float*)d_out;

    const int n = in_sizes[0] / IN_CH;   // 50000
    const int E = in_sizes[1] / 2;       // 800000
    const int* src = ei;
    const int* dst = ei + E;

    // workspace carve-up
    float* dinv   = (float*)d_ws;                        // NPAD
    int*   rowptr = (int*)(dinv + NPAD);                 // NPAD
    int*   cursor = rowptr + NPAD;                       // NPAD
    int2*  erec   = (int2*)(cursor + NPAD);              // E (8B each)
    int*   bsum   = (int*)(erec + 800000);               // 64
    int*   boff   = bsum + 64;                           // 64
    unsigned short* Bt0 = (unsigned short*)(boff + 64);  // 16*256*104
    unsigned short* Bt1 = Bt0 + 16 * HID * 104;          // 8*256*104
    unsigned short* Bt2 = Bt1 + 8 * HID * 104;           // 8*256*104
    _Float16* h16 = (_Float16*)(Bt2 + 8 * HID * 104);    // n*HID fp16
    float* agg32  = (float*)(h16 + (size_t)n * HID);     // n*HID fp32

    const int nb_n = (n + 255) / 256;
    const int nb_e = (E + 255) / 256;
    const int nb_scan = (n + 1023) / 1024;

    // ---- CSR build ----
    hipMemsetAsync(cursor, 0, (size_t)n * 4, stream);
    k_count<<<nb_e, 256, 0, stream>>>(dst, cursor, E);
    k_scan_bsum<<<nb_scan, 256, 0, stream>>>(cursor, bsum, n);
    k_scan_boff<<<1, 64, 0, stream>>>(bsum, boff, nb_scan);
    k_scan_write<<<nb_scan, 256, 0, stream>>>(cursor, boff, rowptr, n);
    k_dinv<<<nb_n, 256, 0, stream>>>(cursor, dinv, n);
    hipMemsetAsync(cursor, 0, (size_t)n * 4, stream);
    k_fill<<<nb_e, 256, 0, stream>>>(src, dst, rowptr, cursor, dinv, erec, E);

    // ---- weight pre-split ----
    k_wsplit<<<(IN_CH * HID) / 256, 256, 0, stream>>>(W0, Bt0, IN_CH);
    k_wsplit<<<(HID * HID) / 256, 256, 0, stream>>>(W1, Bt1, HID);
    k_wsplit<<<(HID * HID) / 256, 256, 0, stream>>>(W2, Bt2, HID);

    const int gemm_blocks = (n + 127) / 128;
    const int agg_blocks = (n + 3) / 4;

    // layer 0
    k_gemm_mfma<false><<<gemm_blocks, 512, 0, stream>>>(x, Bt0, h16, n, IN_CH);
    k_aggregate<false><<<agg_blocks, 256, 0, stream>>>(h16, dinv, rowptr, erec, b0,
                                                       agg32, nullptr, nullptr, nullptr, n);
    // layer 1
    k_gemm_mfma<true><<<gemm_blocks, 512, 0, stream>>>(agg32, Bt1, h16, n, HID);
    k_aggregate<false><<<agg_blocks, 256, 0, stream>>>(h16, dinv, rowptr, erec, b1,
                                                       agg32, nullptr, nullptr, nullptr, n);
    // layer 2 + fused readout
    k_gemm_mfma<true><<<gemm_blocks, 512, 0, stream>>>(agg32, Bt2, h16, n, HID);
    k_aggregate<true><<<agg_blocks, 256, 0, stream>>>(h16, dinv, rowptr, erec, b2,
                                                      nullptr, Wout, bout, out, n);
}